// Round 5
// baseline (222.302 us; speedup 1.0000x reference)
//
#include <hip/hip_runtime.h>
#include <hip/hip_bf16.h>

#define B_N 32
#define SX 2048
#define SY 512
#define DIM 1024
#define NTOK 2
#define DN 128
#define ODIM 1024
#define BM 64

typedef __bf16 bf16;
typedef __bf16 bf16x8 __attribute__((ext_vector_type(8)));
typedef __bf16 bf16x4 __attribute__((ext_vector_type(4)));
typedef float f32x4 __attribute__((ext_vector_type(4)));

__device__ __forceinline__ f32x4 mfma16(bf16x8 a, bf16x8 b, f32x4 c) {
  return __builtin_amdgcn_mfma_f32_16x16x32_bf16(a, b, c, 0, 0, 0);
}

// Convert weights fp32 -> bf16 once per call (weights are small, L2-resident).
__global__ __launch_bounds__(256) void prep_kernel(const float* __restrict__ Wd,
                                                   const float* __restrict__ Wu,
                                                   bf16* __restrict__ wdb,
                                                   bf16* __restrict__ wub) {
  int i = blockIdx.x * 256 + threadIdx.x;
  if (i < DN * DIM) {
    wdb[i] = (bf16)Wd[i];
    wub[i] = (bf16)Wu[i];
  }
}

// tokens[b,t,:] = latent[t] + sum_s softmax_s(latent[t].y[b,s]) * y[b,s]
// Only needed when gate != 0 (slow path; bench has gate == 0).
__global__ __launch_bounds__(256) void tokens_kernel(const float* __restrict__ y,
                                                     const float* __restrict__ lat,
                                                     const float* __restrict__ gate,
                                                     float* __restrict__ tokens) {
  if (gate[0] == 0.0f) return;  // output is independent of tokens in that case
  __shared__ float s_lat[NTOK][DIM];
  __shared__ float s_sc[NTOK][SY];
  int b = blockIdx.x;
  int tid = threadIdx.x, wave = tid >> 6, lane = tid & 63;
  const float* yb = y + (size_t)b * SY * DIM;
  for (int i = tid; i < NTOK * DIM; i += 256) ((float*)s_lat)[i] = lat[i];
  __syncthreads();
  for (int s = wave * 128; s < wave * 128 + 128; ++s) {
    const float* yr = yb + (size_t)s * DIM;
    float d0 = 0.f, d1 = 0.f;
#pragma unroll
    for (int i = 0; i < 4; ++i) {
      f32x4 v = *(const f32x4*)(yr + lane * 4 + i * 256);
      f32x4 l0 = *(const f32x4*)(&s_lat[0][lane * 4 + i * 256]);
      f32x4 l1 = *(const f32x4*)(&s_lat[1][lane * 4 + i * 256]);
      d0 += v[0] * l0[0] + v[1] * l0[1] + v[2] * l0[2] + v[3] * l0[3];
      d1 += v[0] * l1[0] + v[1] * l1[1] + v[2] * l1[2] + v[3] * l1[3];
    }
#pragma unroll
    for (int off = 32; off > 0; off >>= 1) {
      d0 += __shfl_xor(d0, off);
      d1 += __shfl_xor(d1, off);
    }
    if (lane == 0) { s_sc[0][s] = d0; s_sc[1][s] = d1; }
  }
  __syncthreads();
  if (wave < 2) {
    float m = -3.4e38f;
    for (int s = lane; s < SY; s += 64) m = fmaxf(m, s_sc[wave][s]);
#pragma unroll
    for (int off = 32; off > 0; off >>= 1) m = fmaxf(m, __shfl_xor(m, off));
    float sum = 0.f;
    for (int s = lane; s < SY; s += 64) {
      float e = expf(s_sc[wave][s] - m);
      s_sc[wave][s] = e;
      sum += e;
    }
#pragma unroll
    for (int off = 32; off > 0; off >>= 1) sum += __shfl_xor(sum, off);
    float inv = 1.f / sum;
    for (int s = lane; s < SY; s += 64) s_sc[wave][s] *= inv;
  }
  __syncthreads();
  float a0[4] = {0.f, 0.f, 0.f, 0.f}, a1[4] = {0.f, 0.f, 0.f, 0.f};
  for (int s = 0; s < SY; ++s) {
    float p0 = s_sc[0][s], p1 = s_sc[1][s];
    const float* yr = yb + (size_t)s * DIM;
#pragma unroll
    for (int i = 0; i < 4; ++i) {
      float v = yr[tid + i * 256];
      a0[i] += p0 * v;
      a1[i] += p1 * v;
    }
  }
  float* tb = tokens + (size_t)b * NTOK * DIM;
#pragma unroll
  for (int i = 0; i < 4; ++i) {
    tb[tid + i * 256] = s_lat[0][tid + i * 256] + a0[i];
    tb[DIM + tid + i * 256] = s_lat[1][tid + i * 256] + a1[i];
  }
}

// Barrier-free wave-private fused kernel (one barrier total, for Z exchange).
// Block = 4 waves, BM=64 rows, grid 1024 (4 blocks/CU, independent).
// GEMM1 (swapped): Z^T-frag = mfma(Wd-frag, x-frag); wave (wr,wc) owns
//   rows [wr*32,+32) x dn [wc*64,+64). x streamed direct from global with a
//   2-deep register pipeline; Wd direct from global (L1/L2-hot).
// Z exchanged via 16KB swizzled LDS; one __syncthreads.
// GEMM2 (swapped): out^T-frag = mfma(Wu-frag, Z-frag); wave owns all 64 rows
//   x 256 out-cols; Z-frags in registers; packed f32x4 stores.
__global__ __launch_bounds__(256, 4) void main_kernel(const float* __restrict__ x,
                                                      const float* __restrict__ gate,
                                                      const float* __restrict__ tokens,
                                                      const bf16* __restrict__ wdb,
                                                      const bf16* __restrict__ wub,
                                                      float* __restrict__ out) {
  __shared__ bf16 zs_raw[BM * DN];    // 16 KB, XOR-swizzled
  __shared__ float s_tok[NTOK][DIM];  // only touched when gate != 0
  __shared__ float s_c[BM][2];        // only touched when gate != 0

  int tid = threadIdx.x, w = tid >> 6, lane = tid & 63;
  int lq = lane >> 4, lr = lane & 15;
  int wr = w >> 1, wc = w & 1;
  size_t m0 = (size_t)blockIdx.x * BM;
  const float* xb = x + m0 * DIM;
  float g = gate[0];

  float c0m[2] = {0.f, 0.f}, c1m[2] = {0.f, 0.f};
  if (g != 0.f) {
    int b = (int)(m0 / SX);
    const float* tokb = tokens + (size_t)b * NTOK * DIM;
    for (int i = tid; i < NTOK * DIM; i += 256) ((float*)s_tok)[i] = tokb[i];
    __syncthreads();
    // per-wave: softmax-over-2-tokens coeffs for its 16 rows (gate folded in)
    for (int i = 0; i < 16; ++i) {
      int r = w * 16 + i;
      const float* xrow = xb + (size_t)r * DIM;
      float d0 = 0.f, d1 = 0.f;
#pragma unroll
      for (int c = 0; c < 4; ++c) {
        f32x4 v = *(const f32x4*)(xrow + lane * 4 + c * 256);
        f32x4 t0 = *(const f32x4*)(&s_tok[0][lane * 4 + c * 256]);
        f32x4 t1 = *(const f32x4*)(&s_tok[1][lane * 4 + c * 256]);
        d0 += v[0] * t0[0] + v[1] * t0[1] + v[2] * t0[2] + v[3] * t0[3];
        d1 += v[0] * t1[0] + v[1] * t1[1] + v[2] * t1[2] + v[3] * t1[3];
      }
#pragma unroll
      for (int off = 32; off > 0; off >>= 1) {
        d0 += __shfl_xor(d0, off);
        d1 += __shfl_xor(d1, off);
      }
      if (lane == 0) {
        float mm = fmaxf(d0, d1);
        float e0 = expf(d0 - mm), e1 = expf(d1 - mm);
        float inv = g / (e0 + e1);
        s_c[r][0] = e0 * inv;
        s_c[r][1] = e1 * inv;
      }
    }
    __syncthreads();
#pragma unroll
    for (int mt = 0; mt < 2; ++mt) {
      c0m[mt] = s_c[wr * 32 + mt * 16 + lr][0];
      c1m[mt] = s_c[wr * 32 + mt * 16 + lr][1];
    }
  }

  // ---------- GEMM1: barrier-free, 2-deep x register pipeline ----------
  const float* xrow[2];
  const bf16* wdp[4];
#pragma unroll
  for (int mt = 0; mt < 2; ++mt)
    xrow[mt] = xb + (size_t)(wr * 32 + mt * 16 + lr) * DIM + lq * 8;
#pragma unroll
  for (int nf = 0; nf < 4; ++nf)
    wdp[nf] = wdb + (size_t)(wc * 64 + nf * 16 + lr) * DIM + lq * 8;

  f32x4 acc[4][2] = {};  // [nf][mt] : D[dn-frag][xrow-frag]
  f32x4 xA[2][2], xB[2][2];

#pragma unroll
  for (int mt = 0; mt < 2; ++mt) {
    xA[mt][0] = *(const f32x4*)(xrow[mt]);
    xA[mt][1] = *(const f32x4*)(xrow[mt] + 4);
  }

  auto phase = [&](f32x4(&cur)[2][2], f32x4(&nxt)[2][2], int kc, bool pf) {
    if (pf) {
#pragma unroll
      for (int mt = 0; mt < 2; ++mt) {
        nxt[mt][0] = *(const f32x4*)(xrow[mt] + (kc + 1) * 32);
        nxt[mt][1] = *(const f32x4*)(xrow[mt] + (kc + 1) * 32 + 4);
      }
    }
    bf16x8 wdf[4];
#pragma unroll
    for (int nf = 0; nf < 4; ++nf) wdf[nf] = *(const bf16x8*)(wdp[nf] + kc * 32);
    bf16x8 bx[2];
    if (g != 0.f) {
      f32x4 t0a = *(const f32x4*)(&s_tok[0][kc * 32 + lq * 8]);
      f32x4 t0b = *(const f32x4*)(&s_tok[0][kc * 32 + lq * 8 + 4]);
      f32x4 t1a = *(const f32x4*)(&s_tok[1][kc * 32 + lq * 8]);
      f32x4 t1b = *(const f32x4*)(&s_tok[1][kc * 32 + lq * 8 + 4]);
#pragma unroll
      for (int mt = 0; mt < 2; ++mt)
#pragma unroll
        for (int j = 0; j < 4; ++j) {
          bx[mt][j] = (bf16)(cur[mt][0][j] + c0m[mt] * t0a[j] + c1m[mt] * t1a[j]);
          bx[mt][4 + j] = (bf16)(cur[mt][1][j] + c0m[mt] * t0b[j] + c1m[mt] * t1b[j]);
        }
    } else {
#pragma unroll
      for (int mt = 0; mt < 2; ++mt)
#pragma unroll
        for (int j = 0; j < 4; ++j) {
          bx[mt][j] = (bf16)cur[mt][0][j];
          bx[mt][4 + j] = (bf16)cur[mt][1][j];
        }
    }
#pragma unroll
    for (int nf = 0; nf < 4; ++nf)
#pragma unroll
      for (int mt = 0; mt < 2; ++mt)
        acc[nf][mt] = mfma16(wdf[nf], bx[mt], acc[nf][mt]);
  };

  for (int kc2 = 0; kc2 < 16; ++kc2) {
    phase(xA, xB, 2 * kc2, true);
    phase(xB, xA, 2 * kc2 + 1, kc2 < 15);
  }

  // ---------- ReLU -> bf16 Z into swizzled LDS; ONE barrier ----------
  char* zb = (char*)zs_raw;
#pragma unroll
  for (int nf = 0; nf < 4; ++nf)
#pragma unroll
    for (int mt = 0; mt < 2; ++mt) {
      int row = wr * 32 + mt * 16 + lr;        // xrow (D col)
      int dnb = wc * 128 + nf * 32 + lq * 8;   // dn byte offset (D rows)
      bf16x4 pk;
#pragma unroll
      for (int r = 0; r < 4; ++r) pk[r] = (bf16)fmaxf(acc[nf][mt][r], 0.f);
      *(bf16x4*)(zb + row * 256 + (dnb ^ ((row & 7) << 4))) = pk;
    }
  __syncthreads();

  // ---------- GEMM2: Z-frags in regs, Wu streamed, packed stores ----------
  bf16x8 zF[4][4];  // [mt][kkt]
#pragma unroll
  for (int mt = 0; mt < 4; ++mt)
#pragma unroll
    for (int kkt = 0; kkt < 4; ++kkt) {
      int row = mt * 16 + lr;
      zF[mt][kkt] = *(const bf16x8*)(zb + row * 256 + ((kkt * 64 + lq * 16) ^ ((row & 7) << 4)));
    }

  float* ob = out + m0 * ODIM;
#pragma unroll 2
  for (int oc16 = 0; oc16 < 16; ++oc16) {
    int base = w * 256 + oc16 * 16;
    bf16x8 wu[4];
#pragma unroll
    for (int kkt = 0; kkt < 4; ++kkt)
      wu[kkt] = *(const bf16x8*)(wub + (size_t)(base + lr) * DN + kkt * 32 + lq * 8);
    f32x4 a2[4] = {};
#pragma unroll
    for (int kkt = 0; kkt < 4; ++kkt)
#pragma unroll
      for (int mt = 0; mt < 4; ++mt)
        a2[mt] = mfma16(wu[kkt], zF[mt][kkt], a2[mt]);
#pragma unroll
    for (int mt = 0; mt < 4; ++mt)
      *(f32x4*)(ob + (size_t)(mt * 16 + lr) * ODIM + base + lq * 4) = a2[mt];
  }
}

extern "C" void kernel_launch(void* const* d_in, const int* in_sizes, int n_in,
                              void* d_out, int out_size, void* d_ws, size_t ws_size,
                              hipStream_t stream) {
  const float* x = (const float*)d_in[0];
  const float* y = (const float*)d_in[1];
  const float* lat = (const float*)d_in[2];
  const float* gate = (const float*)d_in[3];
  const float* Wd = (const float*)d_in[4];
  const float* Wu = (const float*)d_in[5];
  float* out = (float*)d_out;
  char* ws = (char*)d_ws;

  float* tokens = (float*)ws;              // 32*2*1024*4   = 262144 B
  bf16* wdb = (bf16*)(ws + 262144);        // 128*1024*2    = 262144 B
  bf16* wub = (bf16*)(ws + 524288);        // 1024*128*2    = 262144 B

  prep_kernel<<<(DN * DIM + 255) / 256, 256, 0, stream>>>(Wd, Wu, wdb, wub);
  tokens_kernel<<<B_N, 256, 0, stream>>>(y, lat, gate, tokens);
  main_kernel<<<(B_N * SX) / BM, 256, 0, stream>>>(x, gate, tokens, wdb, wub, out);
}

// Round 6
// 180.456 us; speedup vs baseline: 1.2319x; 1.2319x over previous
//
#include <hip/hip_runtime.h>
#include <hip/hip_bf16.h>

#define B_N 32
#define SX 2048
#define SY 512
#define DIM 1024
#define NTOK 2
#define DN 128
#define ODIM 1024
#define BM 64
#define BK 32
#define KSTEPS (DIM / BK)

typedef __bf16 bf16;
typedef __bf16 bf16x8 __attribute__((ext_vector_type(8)));
typedef float f32x4 __attribute__((ext_vector_type(4)));

typedef __attribute__((address_space(3))) unsigned char lds_u8;
typedef const __attribute__((address_space(1))) unsigned char glb_u8;

__device__ __forceinline__ f32x4 mfma16(bf16x8 a, bf16x8 b, f32x4 c) {
  return __builtin_amdgcn_mfma_f32_16x16x32_bf16(a, b, c, 0, 0, 0);
}

__device__ __forceinline__ void gll16(const void* g, void* l) {
  __builtin_amdgcn_global_load_lds((glb_u8*)g, (lds_u8*)l, 16, 0, 0);
}

// Convert weights fp32 -> bf16 once per call (weights are small, L2-resident).
__global__ __launch_bounds__(256) void prep_kernel(const float* __restrict__ Wd,
                                                   const float* __restrict__ Wu,
                                                   bf16* __restrict__ wdb,
                                                   bf16* __restrict__ wub) {
  int i = blockIdx.x * 256 + threadIdx.x;
  if (i < DN * DIM) {
    wdb[i] = (bf16)Wd[i];
    wub[i] = (bf16)Wu[i];
  }
}

// tokens[b,t,:] = latent[t] + sum_s softmax_s(latent[t].y[b,s]) * y[b,s]
// Only needed when gate != 0 (slow path; bench has gate == 0).
__global__ __launch_bounds__(256) void tokens_kernel(const float* __restrict__ y,
                                                     const float* __restrict__ lat,
                                                     const float* __restrict__ gate,
                                                     float* __restrict__ tokens) {
  if (gate[0] == 0.0f) return;
  __shared__ float s_lat[NTOK][DIM];
  __shared__ float s_sc[NTOK][SY];
  int b = blockIdx.x;
  int tid = threadIdx.x, wave = tid >> 6, lane = tid & 63;
  const float* yb = y + (size_t)b * SY * DIM;
  for (int i = tid; i < NTOK * DIM; i += 256) ((float*)s_lat)[i] = lat[i];
  __syncthreads();
  for (int s = wave * 128; s < wave * 128 + 128; ++s) {
    const float* yr = yb + (size_t)s * DIM;
    float d0 = 0.f, d1 = 0.f;
#pragma unroll
    for (int i = 0; i < 4; ++i) {
      f32x4 v = *(const f32x4*)(yr + lane * 4 + i * 256);
      f32x4 l0 = *(const f32x4*)(&s_lat[0][lane * 4 + i * 256]);
      f32x4 l1 = *(const f32x4*)(&s_lat[1][lane * 4 + i * 256]);
      d0 += v[0] * l0[0] + v[1] * l0[1] + v[2] * l0[2] + v[3] * l0[3];
      d1 += v[0] * l1[0] + v[1] * l1[1] + v[2] * l1[2] + v[3] * l1[3];
    }
#pragma unroll
    for (int off = 32; off > 0; off >>= 1) {
      d0 += __shfl_xor(d0, off);
      d1 += __shfl_xor(d1, off);
    }
    if (lane == 0) { s_sc[0][s] = d0; s_sc[1][s] = d1; }
  }
  __syncthreads();
  if (wave < 2) {
    float m = -3.4e38f;
    for (int s = lane; s < SY; s += 64) m = fmaxf(m, s_sc[wave][s]);
#pragma unroll
    for (int off = 32; off > 0; off >>= 1) m = fmaxf(m, __shfl_xor(m, off));
    float sum = 0.f;
    for (int s = lane; s < SY; s += 64) {
      float e = expf(s_sc[wave][s] - m);
      s_sc[wave][s] = e;
      sum += e;
    }
#pragma unroll
    for (int off = 32; off > 0; off >>= 1) sum += __shfl_xor(sum, off);
    float inv = 1.f / sum;
    for (int s = lane; s < SY; s += 64) s_sc[wave][s] *= inv;
  }
  __syncthreads();
  float a0[4] = {0.f, 0.f, 0.f, 0.f}, a1[4] = {0.f, 0.f, 0.f, 0.f};
  for (int s = 0; s < SY; ++s) {
    float p0 = s_sc[0][s], p1 = s_sc[1][s];
    const float* yr = yb + (size_t)s * DIM;
#pragma unroll
    for (int i = 0; i < 4; ++i) {
      float v = yr[tid + i * 256];
      a0[i] += p0 * v;
      a1[i] += p1 * v;
    }
  }
  float* tb = tokens + (size_t)b * NTOK * DIM;
#pragma unroll
  for (int i = 0; i < 4; ++i) {
    tb[tid + i * 256] = s_lat[0][tid + i * 256] + a0[i];
    tb[DIM + tid + i * 256] = s_lat[1][tid + i * 256] + a1[i];
  }
}

// gate != 0 slow path only: xp[r][:] = x[r][:] + c0(r)*tok0 + c1(r)*tok1,
// written into d_out (main kernel reads each block's rows fully before
// overwriting them with its GEMM2 results).
__global__ __launch_bounds__(256) void xprime_kernel(const float* __restrict__ x,
                                                     const float* __restrict__ gate,
                                                     const float* __restrict__ tokens,
                                                     float* __restrict__ xp) {
  float g = gate[0];
  if (g == 0.0f) return;
  __shared__ float s_tok[NTOK][DIM];
  __shared__ float s_c[BM][2];
  int tid = threadIdx.x, w = tid >> 6, lane = tid & 63;
  size_t m0 = (size_t)blockIdx.x * BM;
  int b = (int)(m0 / SX);
  const float* xb = x + m0 * DIM;
  const float* tokb = tokens + (size_t)b * NTOK * DIM;
  for (int i = tid; i < NTOK * DIM; i += 256) ((float*)s_tok)[i] = tokb[i];
  __syncthreads();
  for (int i = 0; i < 16; ++i) {
    int r = w * 16 + i;
    const float* xrow = xb + (size_t)r * DIM;
    float d0 = 0.f, d1 = 0.f;
#pragma unroll
    for (int c = 0; c < 4; ++c) {
      f32x4 v = *(const f32x4*)(xrow + lane * 4 + c * 256);
      f32x4 t0 = *(const f32x4*)(&s_tok[0][lane * 4 + c * 256]);
      f32x4 t1 = *(const f32x4*)(&s_tok[1][lane * 4 + c * 256]);
      d0 += v[0] * t0[0] + v[1] * t0[1] + v[2] * t0[2] + v[3] * t0[3];
      d1 += v[0] * t1[0] + v[1] * t1[1] + v[2] * t1[2] + v[3] * t1[3];
    }
#pragma unroll
    for (int off = 32; off > 0; off >>= 1) {
      d0 += __shfl_xor(d0, off);
      d1 += __shfl_xor(d1, off);
    }
    if (lane == 0) {
      float mm = fmaxf(d0, d1);
      float e0 = expf(d0 - mm), e1 = expf(d1 - mm);
      float inv = g / (e0 + e1);
      s_c[r][0] = e0 * inv;
      s_c[r][1] = e1 * inv;
    }
  }
  __syncthreads();
  float* xpb = xp + m0 * DIM;
  for (int r = w * 16; r < w * 16 + 16; ++r) {
    float c0 = s_c[r][0], c1 = s_c[r][1];
#pragma unroll
    for (int c = 0; c < 4; ++c) {
      f32x4 v = *(const f32x4*)(xb + (size_t)r * DIM + lane * 4 + c * 256);
      f32x4 t0 = *(const f32x4*)(&s_tok[0][lane * 4 + c * 256]);
      f32x4 t1 = *(const f32x4*)(&s_tok[1][lane * 4 + c * 256]);
      f32x4 o;
#pragma unroll
      for (int j = 0; j < 4; ++j) o[j] = v[j] + c0 * t0[j] + c1 * t1[j];
      *(f32x4*)(xpb + (size_t)r * DIM + lane * 4 + c * 256) = o;
    }
  }
}

// Fused bottleneck: Z = relu(x' Wd^T), out = Z Wu^T.
// m97-structure: both x (fp32) and Wd K-tile (bf16) staged via
// global_load_lds width-16 (no VGPR round trip); compute phase issues ZERO
// vmem (weights from LDS -> lgkmcnt only), so the 4 gll's per iteration stay
// in flight across the whole compute phase. Pre-swizzled global sources +
// XOR-swizzled LDS reads (involution) keep ds_read_b128 conflict-free.
__global__ __launch_bounds__(256, 4) void main_kernel(const float* __restrict__ x,
                                                      const float* __restrict__ gate,
                                                      const float* __restrict__ xp,
                                                      const bf16* __restrict__ wdb,
                                                      const bf16* __restrict__ wub,
                                                      float* __restrict__ out) {
  __shared__ union {
    float xs[2][BM][BK];   // 2 x 8 KB fp32, swizzled
    bf16 zs[BM * DN];      // 16 KB bf16 Z, swizzled (aliases; barriered)
  } u;
  __shared__ bf16 ws_wd[2][DN * BK];  // 2 x 8 KB Wd K-tile, swizzled

  int tid = threadIdx.x, w = tid >> 6, l = tid & 63;
  int lq = l >> 4, lr = l & 15;
  size_t m0 = (size_t)blockIdx.x * BM;
  float g = gate[0];
  const float* src = (g != 0.f) ? xp : x;
  const float* xb = src + m0 * DIM;

  // ---- staging address pre-compute (pre-swizzled global sources) ----
  // x: round i covers rows [i*32,+32); wave w: rows i*32 + w*8 + (l>>3),
  //    chunk (l&7)*16B, swizzle s = (row&7)<<4 = ((l>>3)&7)<<4.
  int xrow0 = w * 8 + (l >> 3);
  int xchunk = ((l & 7) * 16) ^ (((l >> 3) & 7) << 4);
  const char* xg0 = (const char*)xb + (size_t)xrow0 * (DIM * 4) + xchunk;
  char* xl0 = (char*)&u.xs[0][0][0] + w * 1024;  // + buf*8192 + i*4096
  // wd: round i covers dn [i*64,+64); wave w: dn i*64 + w*16 + (l>>2),
  //    chunk (l&3)*16B, swizzle s = (dn&3)<<4 = ((l>>2)&3)<<4.
  int wrow0 = w * 16 + (l >> 2);
  int wchunk = ((l & 3) * 16) ^ (((l >> 2) & 3) << 4);
  const char* wg0 = (const char*)wdb + (size_t)wrow0 * (DIM * 2) + wchunk;
  char* wl0 = (char*)ws_wd + w * 1024;  // + buf*8192 + i*4096

  auto STAGE = [&](int buf, int kc) {
#pragma unroll
    for (int i = 0; i < 2; ++i)
      gll16(xg0 + (size_t)i * 131072 + (size_t)kc * (BK * 4),
            xl0 + buf * 8192 + i * 4096);
#pragma unroll
    for (int i = 0; i < 2; ++i)
      gll16(wg0 + (size_t)i * 131072 + (size_t)kc * (BK * 2),
            wl0 + buf * 8192 + i * 4096);
  };

  f32x4 acc[4][2] = {};

  auto COMPUTE = [&](int buf) {
    const char* xtile = (const char*)&u.xs[buf][0][0];
    const char* wtile = (const char*)ws_wd + buf * 8192;
    bf16x8 bwf[2];
#pragma unroll
    for (int nf = 0; nf < 2; ++nf) {
      int dn = w * 32 + nf * 16 + lr;
      bwf[nf] = *(const bf16x8*)(wtile + dn * 64 + ((lq * 16) ^ ((dn & 3) << 4)));
    }
#pragma unroll
    for (int mt = 0; mt < 4; ++mt) {
      int r = mt * 16 + lr;
      f32x4 a0 = *(const f32x4*)(xtile + r * 128 + ((lq * 32) ^ ((r & 7) << 4)));
      f32x4 a1 = *(const f32x4*)(xtile + r * 128 + ((lq * 32 + 16) ^ ((r & 7) << 4)));
      bf16x8 ax;
#pragma unroll
      for (int j = 0; j < 4; ++j) { ax[j] = (bf16)a0[j]; ax[4 + j] = (bf16)a1[j]; }
      acc[mt][0] = mfma16(ax, bwf[0], acc[mt][0]);
      acc[mt][1] = mfma16(ax, bwf[1], acc[mt][1]);
    }
  };

  // ---- GEMM1 pipeline: issue gll's early, drain only at iteration end ----
  STAGE(0, 0);
  __syncthreads();
#pragma unroll 2
  for (int t = 0; t < KSTEPS; ++t) {
    if (t + 1 < KSTEPS) STAGE((t + 1) & 1, t + 1);  // in flight across compute
    COMPUTE(t & 1);
    __syncthreads();
  }

  // ---- ReLU -> bf16 Z into swizzled LDS (aliases x buffers) ----
  char* zb = (char*)u.zs;
#pragma unroll
  for (int mt = 0; mt < 4; ++mt)
#pragma unroll
    for (int nf = 0; nf < 2; ++nf) {
      int dn = w * 32 + nf * 16 + lr;
#pragma unroll
      for (int reg = 0; reg < 4; ++reg) {
        int row = mt * 16 + lq * 4 + reg;
        float zv = fmaxf(acc[mt][nf][reg], 0.f);
        *(bf16*)(zb + row * (DN * 2) + ((2 * dn) ^ ((row & 7) << 4))) = (bf16)zv;
      }
    }
  __syncthreads();

  // ---- GEMM2: out^T-frag = mfma(Wu-frag, Z-frag); packed f32x4 stores ----
  bf16x8 zF[4][4];  // [mt][kkt]
#pragma unroll
  for (int mt = 0; mt < 4; ++mt)
#pragma unroll
    for (int kkt = 0; kkt < 4; ++kkt) {
      int row = mt * 16 + lr;
      zF[mt][kkt] = *(const bf16x8*)(zb + row * (DN * 2) + ((kkt * 64 + lq * 16) ^ ((row & 7) << 4)));
    }

  float* ob = out + m0 * ODIM;
#pragma unroll 2
  for (int oc16 = 0; oc16 < 16; ++oc16) {
    int base = w * 256 + oc16 * 16;
    bf16x8 wu[4];
#pragma unroll
    for (int kkt = 0; kkt < 4; ++kkt)
      wu[kkt] = *(const bf16x8*)(wub + (size_t)(base + lr) * DN + kkt * 32 + lq * 8);
    f32x4 a2[4] = {};
#pragma unroll
    for (int kkt = 0; kkt < 4; ++kkt)
#pragma unroll
      for (int mt = 0; mt < 4; ++mt)
        a2[mt] = mfma16(wu[kkt], zF[mt][kkt], a2[mt]);
#pragma unroll
    for (int mt = 0; mt < 4; ++mt)
      *(f32x4*)(ob + (size_t)(mt * 16 + lr) * ODIM + base + lq * 4) = a2[mt];
  }
}

extern "C" void kernel_launch(void* const* d_in, const int* in_sizes, int n_in,
                              void* d_out, int out_size, void* d_ws, size_t ws_size,
                              hipStream_t stream) {
  const float* x = (const float*)d_in[0];
  const float* y = (const float*)d_in[1];
  const float* lat = (const float*)d_in[2];
  const float* gate = (const float*)d_in[3];
  const float* Wd = (const float*)d_in[4];
  const float* Wu = (const float*)d_in[5];
  float* out = (float*)d_out;
  char* ws = (char*)d_ws;

  float* tokens = (float*)ws;              // 32*2*1024*4   = 262144 B
  bf16* wdb = (bf16*)(ws + 262144);        // 128*1024*2    = 262144 B
  bf16* wub = (bf16*)(ws + 524288);        // 1024*128*2    = 262144 B

  prep_kernel<<<(DN * DIM + 255) / 256, 256, 0, stream>>>(Wd, Wu, wdb, wub);
  tokens_kernel<<<B_N, 256, 0, stream>>>(y, lat, gate, tokens);
  // gate!=0 only: writes x' into d_out; main reads it back (per-block rows are
  // fully consumed before being overwritten by that block's GEMM2 stores).
  xprime_kernel<<<(B_N * SX) / BM, 256, 0, stream>>>(x, gate, tokens, out);
  main_kernel<<<(B_N * SX) / BM, 256, 0, stream>>>(x, gate, out, wdb, wub, out);
}

// Round 7
// 162.581 us; speedup vs baseline: 1.3673x; 1.1099x over previous
//
#include <hip/hip_runtime.h>
#include <hip/hip_bf16.h>

#define B_N 32
#define SX 2048
#define SY 512
#define DIM 1024
#define NTOK 2
#define DN 128
#define ODIM 1024
#define BM 64
#define KH 512  // K half staged in LDS

typedef __bf16 bf16;
typedef __bf16 bf16x8 __attribute__((ext_vector_type(8)));
typedef __bf16 bf16x4 __attribute__((ext_vector_type(4)));
typedef float f32x4 __attribute__((ext_vector_type(4)));

__device__ __forceinline__ f32x4 mfma16(bf16x8 a, bf16x8 b, f32x4 c) {
  return __builtin_amdgcn_mfma_f32_16x16x32_bf16(a, b, c, 0, 0, 0);
}

// Convert weights fp32 -> bf16 once per call (weights are small, L2-resident).
__global__ __launch_bounds__(256) void prep_kernel(const float* __restrict__ Wd,
                                                   const float* __restrict__ Wu,
                                                   bf16* __restrict__ wdb,
                                                   bf16* __restrict__ wub) {
  int i = blockIdx.x * 256 + threadIdx.x;
  if (i < DN * DIM) {
    wdb[i] = (bf16)Wd[i];
    wub[i] = (bf16)Wu[i];
  }
}

// tokens[b,t,:] = latent[t] + sum_s softmax_s(latent[t].y[b,s]) * y[b,s]
// Only needed when gate != 0 (slow path; bench has gate == 0).
__global__ __launch_bounds__(256) void tokens_kernel(const float* __restrict__ y,
                                                     const float* __restrict__ lat,
                                                     const float* __restrict__ gate,
                                                     float* __restrict__ tokens) {
  if (gate[0] == 0.0f) return;
  __shared__ float s_lat[NTOK][DIM];
  __shared__ float s_sc[NTOK][SY];
  int b = blockIdx.x;
  int tid = threadIdx.x, wave = tid >> 6, lane = tid & 63;
  const float* yb = y + (size_t)b * SY * DIM;
  for (int i = tid; i < NTOK * DIM; i += 256) ((float*)s_lat)[i] = lat[i];
  __syncthreads();
  for (int s = wave * 128; s < wave * 128 + 128; ++s) {
    const float* yr = yb + (size_t)s * DIM;
    float d0 = 0.f, d1 = 0.f;
#pragma unroll
    for (int i = 0; i < 4; ++i) {
      f32x4 v = *(const f32x4*)(yr + lane * 4 + i * 256);
      f32x4 l0 = *(const f32x4*)(&s_lat[0][lane * 4 + i * 256]);
      f32x4 l1 = *(const f32x4*)(&s_lat[1][lane * 4 + i * 256]);
      d0 += v[0] * l0[0] + v[1] * l0[1] + v[2] * l0[2] + v[3] * l0[3];
      d1 += v[0] * l1[0] + v[1] * l1[1] + v[2] * l1[2] + v[3] * l1[3];
    }
#pragma unroll
    for (int off = 32; off > 0; off >>= 1) {
      d0 += __shfl_xor(d0, off);
      d1 += __shfl_xor(d1, off);
    }
    if (lane == 0) { s_sc[0][s] = d0; s_sc[1][s] = d1; }
  }
  __syncthreads();
  if (wave < 2) {
    float m = -3.4e38f;
    for (int s = lane; s < SY; s += 64) m = fmaxf(m, s_sc[wave][s]);
#pragma unroll
    for (int off = 32; off > 0; off >>= 1) m = fmaxf(m, __shfl_xor(m, off));
    float sum = 0.f;
    for (int s = lane; s < SY; s += 64) {
      float e = expf(s_sc[wave][s] - m);
      s_sc[wave][s] = e;
      sum += e;
    }
#pragma unroll
    for (int off = 32; off > 0; off >>= 1) sum += __shfl_xor(sum, off);
    float inv = 1.f / sum;
    for (int s = lane; s < SY; s += 64) s_sc[wave][s] *= inv;
  }
  __syncthreads();
  float a0[4] = {0.f, 0.f, 0.f, 0.f}, a1[4] = {0.f, 0.f, 0.f, 0.f};
  for (int s = 0; s < SY; ++s) {
    float p0 = s_sc[0][s], p1 = s_sc[1][s];
    const float* yr = yb + (size_t)s * DIM;
#pragma unroll
    for (int i = 0; i < 4; ++i) {
      float v = yr[tid + i * 256];
      a0[i] += p0 * v;
      a1[i] += p1 * v;
    }
  }
  float* tb = tokens + (size_t)b * NTOK * DIM;
#pragma unroll
  for (int i = 0; i < 4; ++i) {
    tb[tid + i * 256] = s_lat[0][tid + i * 256] + a0[i];
    tb[DIM + tid + i * 256] = s_lat[1][tid + i * 256] + a1[i];
  }
}

// gate != 0 slow path only: xp[r][:] = x[r][:] + c0(r)*tok0 + c1(r)*tok1,
// written into d_out (main kernel reads each block's rows fully before
// overwriting them with its GEMM2 results).
__global__ __launch_bounds__(256) void xprime_kernel(const float* __restrict__ x,
                                                     const float* __restrict__ gate,
                                                     const float* __restrict__ tokens,
                                                     float* __restrict__ xp) {
  float g = gate[0];
  if (g == 0.0f) return;
  __shared__ float s_tok[NTOK][DIM];
  __shared__ float s_c[BM][2];
  int tid = threadIdx.x, w = tid >> 6, lane = tid & 63;
  size_t m0 = (size_t)blockIdx.x * BM;
  int b = (int)(m0 / SX);
  const float* xb = x + m0 * DIM;
  const float* tokb = tokens + (size_t)b * NTOK * DIM;
  for (int i = tid; i < NTOK * DIM; i += 256) ((float*)s_tok)[i] = tokb[i];
  __syncthreads();
  for (int i = 0; i < 16; ++i) {
    int r = w * 16 + i;
    const float* xrow = xb + (size_t)r * DIM;
    float d0 = 0.f, d1 = 0.f;
#pragma unroll
    for (int c = 0; c < 4; ++c) {
      f32x4 v = *(const f32x4*)(xrow + lane * 4 + c * 256);
      f32x4 t0 = *(const f32x4*)(&s_tok[0][lane * 4 + c * 256]);
      f32x4 t1 = *(const f32x4*)(&s_tok[1][lane * 4 + c * 256]);
      d0 += v[0] * t0[0] + v[1] * t0[1] + v[2] * t0[2] + v[3] * t0[3];
      d1 += v[0] * t1[0] + v[1] * t1[1] + v[2] * t1[2] + v[3] * t1[3];
    }
#pragma unroll
    for (int off = 32; off > 0; off >>= 1) {
      d0 += __shfl_xor(d0, off);
      d1 += __shfl_xor(d1, off);
    }
    if (lane == 0) {
      float mm = fmaxf(d0, d1);
      float e0 = expf(d0 - mm), e1 = expf(d1 - mm);
      float inv = g / (e0 + e1);
      s_c[r][0] = e0 * inv;
      s_c[r][1] = e1 * inv;
    }
  }
  __syncthreads();
  float* xpb = xp + m0 * DIM;
  for (int r = w * 16; r < w * 16 + 16; ++r) {
    float c0 = s_c[r][0], c1 = s_c[r][1];
#pragma unroll
    for (int c = 0; c < 4; ++c) {
      f32x4 v = *(const f32x4*)(xb + (size_t)r * DIM + lane * 4 + c * 256);
      f32x4 t0 = *(const f32x4*)(&s_tok[0][lane * 4 + c * 256]);
      f32x4 t1 = *(const f32x4*)(&s_tok[1][lane * 4 + c * 256]);
      f32x4 o;
#pragma unroll
      for (int j = 0; j < 4; ++j) o[j] = v[j] + c0 * t0[j] + c1 * t1[j];
      *(f32x4*)(xpb + (size_t)r * DIM + lane * 4 + c * 256) = o;
    }
  }
}

// Phase-separated fused bottleneck: Z = relu(x' Wd^T), out = Z Wu^T.
// No barriers inside any K-loop. Per block (8 waves, 64 rows):
//   LOAD(h): whole x half-panel (64x512) streamed SEQUENTIALLY (each wave
//            reads full 2KB row-halves; 16 dwordx4 in flight per wave),
//            cvt bf16 -> swizzled LDS.           [barrier]
//   COMP(h): GEMM1 K-half from stable LDS, Wd streamed from L2, acc in regs.
//            Compiler pipelines freely (no barriers).   [barrier]
//   ReLU -> Z (16KB LDS)  [barrier]  GEMM2 swapped-operand, packed stores.
__global__ __launch_bounds__(512, 4) void main_kernel(const float* __restrict__ x,
                                                      const float* __restrict__ gate,
                                                      const float* __restrict__ xp,
                                                      const bf16* __restrict__ wdb,
                                                      const bf16* __restrict__ wub,
                                                      float* __restrict__ out) {
  __shared__ bf16 xs[BM * KH];   // 64 KB, XOR-swizzled
  __shared__ bf16 zsm[BM * DN];  // 16 KB, XOR-swizzled

  int tid = threadIdx.x, w = tid >> 6, lane = tid & 63;
  int lq = lane >> 4, lr = lane & 15;
  size_t m0 = (size_t)blockIdx.x * BM;
  float g = gate[0];
  const float* xb = ((g != 0.f) ? xp : x) + m0 * DIM;

  char* xls = (char*)xs;
  char* zls = (char*)zsm;

  f32x4 acc[4] = {};

  // ---------------- LOAD(h): sequential burst, 16 loads in flight ----------
  auto LOADH = [&](int h) {
    f32x4 xv[8][2];
#pragma unroll
    for (int i = 0; i < 8; ++i) {
      int row = w + i * 8;  // wave w owns rows {w, w+8, ..., w+56}
      const float* p = xb + (size_t)row * DIM + h * KH + lane * 8;
      xv[i][0] = *(const f32x4*)p;
      xv[i][1] = *(const f32x4*)(p + 4);
    }
#pragma unroll
    for (int i = 0; i < 8; ++i) {
      int row = w + i * 8;  // row & 7 == w
      bf16x8 o;
#pragma unroll
      for (int j = 0; j < 4; ++j) {
        o[j] = (bf16)xv[i][0][j];
        o[4 + j] = (bf16)xv[i][1][j];
      }
      *(bf16x8*)(xls + row * (KH * 2) + ((lane * 16) ^ (w << 4))) = o;
    }
  };

  // ---------------- COMP(h): barrier-free GEMM1 K-half ---------------------
  auto COMPH = [&](int h) {
    const bf16* wdw = wdb + (size_t)(w * 16 + lr) * DIM + h * KH + lq * 8;
#pragma unroll 4
    for (int kc = 0; kc < KH / 32; ++kc) {
      bf16x8 wf = *(const bf16x8*)(wdw + kc * 32);  // A-frag: Wd[dn][k] from L2
#pragma unroll
      for (int mt = 0; mt < 4; ++mt) {
        int xr = mt * 16 + lr;
        bf16x8 xf = *(const bf16x8*)(xls + xr * (KH * 2) +
                                     (((kc * 32 + lq * 8) * 2) ^ ((xr & 7) << 4)));
        acc[mt] = mfma16(wf, xf, acc[mt]);  // D[dn-local][xr]
      }
    }
  };

  LOADH(0);
  __syncthreads();
  COMPH(0);
  __syncthreads();  // xs stable until here; about to overwrite
  LOADH(1);
  __syncthreads();
  COMPH(1);

  // ---------------- ReLU -> bf16 Z into swizzled LDS ----------------------
#pragma unroll
  for (int mt = 0; mt < 4; ++mt) {
    int xr = mt * 16 + lr;
    int dn = w * 16 + lq * 4;  // regs r -> consecutive dn
    bf16x4 pk;
#pragma unroll
    for (int r = 0; r < 4; ++r) pk[r] = (bf16)fmaxf(acc[mt][r], 0.f);
    *(bf16x4*)(zls + xr * (DN * 2) + ((dn * 2) ^ ((xr & 7) << 4))) = pk;
  }
  __syncthreads();

  // ---------------- GEMM2: out^T-frag = mfma(Wu, Z); packed stores --------
  bf16x8 zF[4][4];  // [kt][mt]
#pragma unroll
  for (int mt = 0; mt < 4; ++mt)
#pragma unroll
    for (int kt = 0; kt < 4; ++kt) {
      int xr = mt * 16 + lr;
      zF[kt][mt] = *(const bf16x8*)(zls + xr * (DN * 2) +
                                    (((kt * 32 + lq * 8) * 2) ^ ((xr & 7) << 4)));
    }

  float* ob = out + m0 * ODIM;
#pragma unroll 2
  for (int oc16 = 0; oc16 < 8; ++oc16) {
    int base = w * 128 + oc16 * 16;  // wave w owns out cols [w*128, +128)
    bf16x8 wu[4];
#pragma unroll
    for (int kt = 0; kt < 4; ++kt)
      wu[kt] = *(const bf16x8*)(wub + (size_t)(base + lr) * DN + kt * 32 + lq * 8);
    f32x4 a2[4] = {};
#pragma unroll
    for (int kt = 0; kt < 4; ++kt)
#pragma unroll
      for (int mt = 0; mt < 4; ++mt)
        a2[mt] = mfma16(wu[kt], zF[kt][mt], a2[mt]);
#pragma unroll
    for (int mt = 0; mt < 4; ++mt)
      *(f32x4*)(ob + (size_t)(mt * 16 + lr) * ODIM + base + lq * 4) = a2[mt];
  }
}

extern "C" void kernel_launch(void* const* d_in, const int* in_sizes, int n_in,
                              void* d_out, int out_size, void* d_ws, size_t ws_size,
                              hipStream_t stream) {
  const float* x = (const float*)d_in[0];
  const float* y = (const float*)d_in[1];
  const float* lat = (const float*)d_in[2];
  const float* gate = (const float*)d_in[3];
  const float* Wd = (const float*)d_in[4];
  const float* Wu = (const float*)d_in[5];
  float* out = (float*)d_out;
  char* ws = (char*)d_ws;

  float* tokens = (float*)ws;              // 32*2*1024*4   = 262144 B
  bf16* wdb = (bf16*)(ws + 262144);        // 128*1024*2    = 262144 B
  bf16* wub = (bf16*)(ws + 524288);        // 1024*128*2    = 262144 B

  prep_kernel<<<(DN * DIM + 255) / 256, 256, 0, stream>>>(Wd, Wu, wdb, wub);
  tokens_kernel<<<B_N, 256, 0, stream>>>(y, lat, gate, tokens);
  // gate!=0 only: writes x' into d_out; main reads it back (per-block rows are
  // fully consumed before being overwritten by that block's GEMM2 stores).
  xprime_kernel<<<(B_N * SX) / BM, 256, 0, stream>>>(x, gate, tokens, out);
  main_kernel<<<(B_N * SX) / BM, 512, 0, stream>>>(x, gate, out, wdb, wub, out);
}

// Round 8
// 159.657 us; speedup vs baseline: 1.3924x; 1.0183x over previous
//
#include <hip/hip_runtime.h>
#include <hip/hip_bf16.h>

#define B_N 32
#define SX 2048
#define SY 512
#define DIM 1024
#define NTOK 2
#define DN 128
#define ODIM 1024
#define BM 64
#define QK 256  // K quarter staged in LDS
#define NQ 4

typedef __bf16 bf16;
typedef __bf16 bf16x8 __attribute__((ext_vector_type(8)));
typedef __bf16 bf16x4 __attribute__((ext_vector_type(4)));
typedef float f32x4 __attribute__((ext_vector_type(4)));

__device__ __forceinline__ f32x4 mfma16(bf16x8 a, bf16x8 b, f32x4 c) {
  return __builtin_amdgcn_mfma_f32_16x16x32_bf16(a, b, c, 0, 0, 0);
}

// Convert weights fp32 -> bf16 once per call (weights are small, L2-resident).
__global__ __launch_bounds__(256) void prep_kernel(const float* __restrict__ Wd,
                                                   const float* __restrict__ Wu,
                                                   bf16* __restrict__ wdb,
                                                   bf16* __restrict__ wub) {
  int i = blockIdx.x * 256 + threadIdx.x;
  if (i < DN * DIM) {
    wdb[i] = (bf16)Wd[i];
    wub[i] = (bf16)Wu[i];
  }
}

// tokens[b,t,:] = latent[t] + sum_s softmax_s(latent[t].y[b,s]) * y[b,s]
// Only needed when gate != 0 (slow path; bench has gate == 0).
__global__ __launch_bounds__(256) void tokens_kernel(const float* __restrict__ y,
                                                     const float* __restrict__ lat,
                                                     const float* __restrict__ gate,
                                                     float* __restrict__ tokens) {
  if (gate[0] == 0.0f) return;
  __shared__ float s_lat[NTOK][DIM];
  __shared__ float s_sc[NTOK][SY];
  int b = blockIdx.x;
  int tid = threadIdx.x, wave = tid >> 6, lane = tid & 63;
  const float* yb = y + (size_t)b * SY * DIM;
  for (int i = tid; i < NTOK * DIM; i += 256) ((float*)s_lat)[i] = lat[i];
  __syncthreads();
  for (int s = wave * 128; s < wave * 128 + 128; ++s) {
    const float* yr = yb + (size_t)s * DIM;
    float d0 = 0.f, d1 = 0.f;
#pragma unroll
    for (int i = 0; i < 4; ++i) {
      f32x4 v = *(const f32x4*)(yr + lane * 4 + i * 256);
      f32x4 l0 = *(const f32x4*)(&s_lat[0][lane * 4 + i * 256]);
      f32x4 l1 = *(const f32x4*)(&s_lat[1][lane * 4 + i * 256]);
      d0 += v[0] * l0[0] + v[1] * l0[1] + v[2] * l0[2] + v[3] * l0[3];
      d1 += v[0] * l1[0] + v[1] * l1[1] + v[2] * l1[2] + v[3] * l1[3];
    }
#pragma unroll
    for (int off = 32; off > 0; off >>= 1) {
      d0 += __shfl_xor(d0, off);
      d1 += __shfl_xor(d1, off);
    }
    if (lane == 0) { s_sc[0][s] = d0; s_sc[1][s] = d1; }
  }
  __syncthreads();
  if (wave < 2) {
    float m = -3.4e38f;
    for (int s = lane; s < SY; s += 64) m = fmaxf(m, s_sc[wave][s]);
#pragma unroll
    for (int off = 32; off > 0; off >>= 1) m = fmaxf(m, __shfl_xor(m, off));
    float sum = 0.f;
    for (int s = lane; s < SY; s += 64) {
      float e = expf(s_sc[wave][s] - m);
      s_sc[wave][s] = e;
      sum += e;
    }
#pragma unroll
    for (int off = 32; off > 0; off >>= 1) sum += __shfl_xor(sum, off);
    float inv = 1.f / sum;
    for (int s = lane; s < SY; s += 64) s_sc[wave][s] *= inv;
  }
  __syncthreads();
  float a0[4] = {0.f, 0.f, 0.f, 0.f}, a1[4] = {0.f, 0.f, 0.f, 0.f};
  for (int s = 0; s < SY; ++s) {
    float p0 = s_sc[0][s], p1 = s_sc[1][s];
    const float* yr = yb + (size_t)s * DIM;
#pragma unroll
    for (int i = 0; i < 4; ++i) {
      float v = yr[tid + i * 256];
      a0[i] += p0 * v;
      a1[i] += p1 * v;
    }
  }
  float* tb = tokens + (size_t)b * NTOK * DIM;
#pragma unroll
  for (int i = 0; i < 4; ++i) {
    tb[tid + i * 256] = s_lat[0][tid + i * 256] + a0[i];
    tb[DIM + tid + i * 256] = s_lat[1][tid + i * 256] + a1[i];
  }
}

// gate != 0 slow path only: xp[r][:] = x[r][:] + c0(r)*tok0 + c1(r)*tok1,
// written into d_out (main kernel reads each block's rows fully before
// overwriting them with its GEMM2 results).
__global__ __launch_bounds__(256) void xprime_kernel(const float* __restrict__ x,
                                                     const float* __restrict__ gate,
                                                     const float* __restrict__ tokens,
                                                     float* __restrict__ xp) {
  float g = gate[0];
  if (g == 0.0f) return;
  __shared__ float s_tok[NTOK][DIM];
  __shared__ float s_c[BM][2];
  int tid = threadIdx.x, w = tid >> 6, lane = tid & 63;
  size_t m0 = (size_t)blockIdx.x * BM;
  int b = (int)(m0 / SX);
  const float* xb = x + m0 * DIM;
  const float* tokb = tokens + (size_t)b * NTOK * DIM;
  for (int i = tid; i < NTOK * DIM; i += 256) ((float*)s_tok)[i] = tokb[i];
  __syncthreads();
  for (int i = 0; i < 16; ++i) {
    int r = w * 16 + i;
    const float* xrow = xb + (size_t)r * DIM;
    float d0 = 0.f, d1 = 0.f;
#pragma unroll
    for (int c = 0; c < 4; ++c) {
      f32x4 v = *(const f32x4*)(xrow + lane * 4 + c * 256);
      f32x4 t0 = *(const f32x4*)(&s_tok[0][lane * 4 + c * 256]);
      f32x4 t1 = *(const f32x4*)(&s_tok[1][lane * 4 + c * 256]);
      d0 += v[0] * t0[0] + v[1] * t0[1] + v[2] * t0[2] + v[3] * t0[3];
      d1 += v[0] * t1[0] + v[1] * t1[1] + v[2] * t1[2] + v[3] * t1[3];
    }
#pragma unroll
    for (int off = 32; off > 0; off >>= 1) {
      d0 += __shfl_xor(d0, off);
      d1 += __shfl_xor(d1, off);
    }
    if (lane == 0) {
      float mm = fmaxf(d0, d1);
      float e0 = expf(d0 - mm), e1 = expf(d1 - mm);
      float inv = g / (e0 + e1);
      s_c[r][0] = e0 * inv;
      s_c[r][1] = e1 * inv;
    }
  }
  __syncthreads();
  float* xpb = xp + m0 * DIM;
  for (int r = w * 16; r < w * 16 + 16; ++r) {
    float c0 = s_c[r][0], c1 = s_c[r][1];
#pragma unroll
    for (int c = 0; c < 4; ++c) {
      f32x4 v = *(const f32x4*)(xb + (size_t)r * DIM + lane * 4 + c * 256);
      f32x4 t0 = *(const f32x4*)(&s_tok[0][lane * 4 + c * 256]);
      f32x4 t1 = *(const f32x4*)(&s_tok[1][lane * 4 + c * 256]);
      f32x4 o;
#pragma unroll
      for (int j = 0; j < 4; ++j) o[j] = v[j] + c0 * t0[j] + c1 * t1[j];
      *(f32x4*)(xpb + (size_t)r * DIM + lane * 4 + c * 256) = o;
    }
  }
}

// T14 pipelined fused bottleneck: Z = relu(x' Wd^T), out = Z Wu^T.
// Per K-quarter: issue next x loads (regs) BEFORE compute; COMP runs from
// LDS + register-resident Wd (zero VMEM waits inside); issue next Wd after
// COMP; barrier; cvt+write staged x (vmcnt drain lands after compute);
// barrier. Loads stay outstanding ~85% of the time.
__global__ __launch_bounds__(512, 4) void main_kernel(const float* __restrict__ x,
                                                      const float* __restrict__ gate,
                                                      const float* __restrict__ xp,
                                                      const bf16* __restrict__ wdb,
                                                      const bf16* __restrict__ wub,
                                                      float* __restrict__ out) {
  __shared__ bf16 xq[2][BM * QK];  // 2 x 32 KB, XOR-swizzled
  __shared__ bf16 zsm[BM * DN];    // 16 KB, XOR-swizzled

  int tid = threadIdx.x, w = tid >> 6, lane = tid & 63;
  int lq = lane >> 4, lr = lane & 15;
  size_t m0 = (size_t)blockIdx.x * BM;
  float g = gate[0];
  const float* xb = ((g != 0.f) ? xp : x) + m0 * DIM;

  // staging map: load i in 0..3 -> row = i*16 + (tid>>5), float col = (tid&31)*8
  int srow = tid >> 5;
  int scolb = (tid & 31) * 16;  // bf16 byte offset within row (0..496)
  const float* xgp = xb + (size_t)srow * DIM + (tid & 31) * 8;

  f32x4 xs0[4], xs1[4];  // 32 VGPR staging
  bf16x8 wdr[8];         // 32 VGPR Wd quarter-slice
  f32x4 acc[4] = {};

  const bf16* wdp = wdb + (size_t)(w * 16 + lr) * DIM + lq * 8;

  char* xls = (char*)xq;
  char* zls = (char*)zsm;

  auto XLOAD = [&](int q) {
#pragma unroll
    for (int i = 0; i < 4; ++i) {
      const float* p = xgp + (size_t)i * 16 * DIM + q * QK;
      xs0[i] = *(const f32x4*)p;
      xs1[i] = *(const f32x4*)(p + 4);
    }
  };
  auto WLOAD = [&](int q) {
#pragma unroll
    for (int kc = 0; kc < 8; ++kc)
      wdr[kc] = *(const bf16x8*)(wdp + q * QK + kc * 32);
  };
  auto XWRITE = [&](int buf) {
    char* base = xls + buf * (BM * QK * 2);
#pragma unroll
    for (int i = 0; i < 4; ++i) {
      int row = i * 16 + srow;
      bf16x8 o;
#pragma unroll
      for (int j = 0; j < 4; ++j) {
        o[j] = (bf16)xs0[i][j];
        o[4 + j] = (bf16)xs1[i][j];
      }
      *(bf16x8*)(base + row * (QK * 2) + (scolb ^ ((row & 7) << 4))) = o;
    }
  };
  auto COMP = [&](int buf) {
    const char* base = xls + buf * (BM * QK * 2);
#pragma unroll
    for (int kc = 0; kc < 8; ++kc) {
#pragma unroll
      for (int mt = 0; mt < 4; ++mt) {
        int row = mt * 16 + lr;
        bf16x8 xf = *(const bf16x8*)(base + row * (QK * 2) +
                                     ((kc * 64 + lq * 16) ^ ((row & 7) << 4)));
        acc[mt] = mfma16(wdr[kc], xf, acc[mt]);  // D[dn-slice][xrow]
      }
    }
  };

  // prologue
  XLOAD(0);
  WLOAD(0);
  XWRITE(0);  // waits x loads; wd still in flight
  __syncthreads();

#pragma unroll
  for (int q = 0; q < NQ; ++q) {
    if (q + 1 < NQ) XLOAD(q + 1);  // in flight across COMP + barrier
    COMP(q & 1);                   // LDS + regs only; no vmem waits
    if (q + 1 < NQ) WLOAD(q + 1);  // safe: MFMAs already issued (in-order wave)
    __syncthreads();               // all waves done reading xq[q&1]
    if (q + 1 < NQ) XWRITE((q + 1) & 1);  // vmcnt drain happens here
    __syncthreads();
  }

  // ---- ReLU -> bf16 Z into swizzled LDS ----
#pragma unroll
  for (int mt = 0; mt < 4; ++mt) {
    int xr = mt * 16 + lr;
    int dn = w * 16 + lq * 4;
    bf16x4 pk;
#pragma unroll
    for (int r = 0; r < 4; ++r) pk[r] = (bf16)fmaxf(acc[mt][r], 0.f);
    *(bf16x4*)(zls + xr * (DN * 2) + ((dn * 2) ^ ((xr & 7) << 4))) = pk;
  }
  __syncthreads();

  // ---- GEMM2: out^T-frag = mfma(Wu, Z); packed f32x4 stores ----
  bf16x8 zF[4][4];  // [kt][mt]
#pragma unroll
  for (int mt = 0; mt < 4; ++mt)
#pragma unroll
    for (int kt = 0; kt < 4; ++kt) {
      int xr = mt * 16 + lr;
      zF[kt][mt] = *(const bf16x8*)(zls + xr * (DN * 2) +
                                    (((kt * 32 + lq * 8) * 2) ^ ((xr & 7) << 4)));
    }

  float* ob = out + m0 * ODIM;
#pragma unroll 2
  for (int oc16 = 0; oc16 < 8; ++oc16) {
    int base = w * 128 + oc16 * 16;  // wave w owns out cols [w*128, +128)
    bf16x8 wu[4];
#pragma unroll
    for (int kt = 0; kt < 4; ++kt)
      wu[kt] = *(const bf16x8*)(wub + (size_t)(base + lr) * DN + kt * 32 + lq * 8);
    f32x4 a2[4] = {};
#pragma unroll
    for (int kt = 0; kt < 4; ++kt)
#pragma unroll
      for (int mt = 0; mt < 4; ++mt)
        a2[mt] = mfma16(wu[kt], zF[kt][mt], a2[mt]);
#pragma unroll
    for (int mt = 0; mt < 4; ++mt)
      *(f32x4*)(ob + (size_t)(mt * 16 + lr) * ODIM + base + lq * 4) = a2[mt];
  }
}

extern "C" void kernel_launch(void* const* d_in, const int* in_sizes, int n_in,
                              void* d_out, int out_size, void* d_ws, size_t ws_size,
                              hipStream_t stream) {
  const float* x = (const float*)d_in[0];
  const float* y = (const float*)d_in[1];
  const float* lat = (const float*)d_in[2];
  const float* gate = (const float*)d_in[3];
  const float* Wd = (const float*)d_in[4];
  const float* Wu = (const float*)d_in[5];
  float* out = (float*)d_out;
  char* ws = (char*)d_ws;

  float* tokens = (float*)ws;              // 32*2*1024*4   = 262144 B
  bf16* wdb = (bf16*)(ws + 262144);        // 128*1024*2    = 262144 B
  bf16* wub = (bf16*)(ws + 524288);        // 1024*128*2    = 262144 B

  prep_kernel<<<(DN * DIM + 255) / 256, 256, 0, stream>>>(Wd, Wu, wdb, wub);
  tokens_kernel<<<B_N, 256, 0, stream>>>(y, lat, gate, tokens);
  // gate!=0 only: writes x' into d_out; main reads it back (per-block rows are
  // fully consumed before being overwritten by that block's GEMM2 stores).
  xprime_kernel<<<(B_N * SX) / BM, 256, 0, stream>>>(x, gate, tokens, out);
  main_kernel<<<(B_N * SX) / BM, 512, 0, stream>>>(x, gate, out, wdb, wub, out);
}